// Round 4
// baseline (378.733 us; speedup 1.0000x reference)
//
#include <hip/hip_runtime.h>
#include <hip/hip_bf16.h>
#include <hip/hip_fp16.h>

// Problem constants
#define B_    2
#define G_    16
#define N_    4096
#define S_    1024
#define D1_   128
#define D2_   256
#define CIN_  384
#define BG_   32
#define GN_   65536
#define GS_   16384

typedef unsigned int u32;
typedef unsigned short u16;
typedef _Float16 f16x8 __attribute__((ext_vector_type(8)));
typedef float f32x4 __attribute__((ext_vector_type(4)));

__device__ __forceinline__ u32 h2bits(__half2 h) { union { __half2 h; u32 u; } c; c.h = h; return c.u; }
__device__ __forceinline__ __half2 bits2h(u32 u) { union { __half2 h; u32 u; } c; c.u = u; return c.h; }
__device__ __forceinline__ u32 pkmax0(u32 v) {
  u32 r; asm("v_pk_max_f16 %0, %1, %2" : "=v"(r) : "v"(v), "v"(0)); return r;
}

// ---------------- workspace layout (bytes) ----------------
#define OFF_W1H    0u           // 256*384*2
#define OFF_W2H    196608u      // 256*256*2
#define OFF_XYZ2P  327680u      // 32*256*4*16
#define OFF_SUM1   851968u      // 4*4096*4 total (sum1,sq1,sum2,sq2)
#define OFF_SQ1    868352u
#define OFF_SUM2   884736u
#define OFF_SQ2    901120u
#define OFF_SCPK1  917504u      // 16*128*4 = 8192 (packed half2 scale, BN1)
#define OFF_SHPK1  925696u      // 8192 (packed half2 shift, BN1)
#define OFF_SS2    950272u      // 16*256*8 = 32768 (float2, BN2)
#define OFF_KNNW   983040u
#define OFF_KNNI   3080192u
#define OFF_P2T    5177344u     // 32*1024*256*2 f16
#define OFF_Y2     21954560u    // f16 pre-BN2, OUT layout [b][m][gn]
#define OFF_Y1     122617856u   // f16 pre-BN1, [bg*4096+n][256]

// ---------------- prep: weights->f16, zero stats, pack xyz2 ----------------
__launch_bounds__(256)
__global__ void prep_kernel(const float* __restrict__ W1, const float* __restrict__ W2,
                            const float* __restrict__ xyz2,
                            u16* __restrict__ W1h, u16* __restrict__ W2h,
                            float4* __restrict__ xyz2p, float* __restrict__ zeros)
{
  int idx = blockIdx.x * 256 + threadIdx.x;
  if (idx < 98304) { W1h[idx] = __half_as_ushort(__float2half_rn(W1[idx])); return; }
  idx -= 98304;
  if (idx < 65536) { W2h[idx] = __half_as_ushort(__float2half_rn(W2[idx])); return; }
  idx -= 65536;
  if (idx < 16384) { zeros[idx] = 0.f; return; }
  idx -= 16384;
  int bg = idx >> 8, q = idx & 255;
  int b = bg >> 4, g = bg & 15;
  const float* base = xyz2 + (size_t)b * 3 * GS_ + (size_t)g * S_ + q * 4;
  float4 X = *(const float4*)(base);
  float4 Y = *(const float4*)(base + GS_);
  float4 Z = *(const float4*)(base + 2 * GS_);
  float4 M;
  M.x = X.x*X.x + Y.x*Y.x + Z.x*Z.x;
  M.y = X.y*X.y + Y.y*Y.y + Z.y*Z.y;
  M.z = X.z*X.z + Y.z*Y.z + Z.z*Z.z;
  M.w = X.w*X.w + Y.w*Y.w + Z.w*Z.w;
  float4* dst = xyz2p + (size_t)idx * 4;
  dst[0] = X; dst[1] = Y; dst[2] = Z; dst[3] = M;
}

// ---------------- transpose points2 -> p2T [s][256] f16 ----------------
__launch_bounds__(256)
__global__ void t2_kernel(const float* __restrict__ p2, u16* __restrict__ p2T)
{
  __shared__ float tl[64][65];
  int bx = blockIdx.x;
  int bg = bx >> 6, r = bx & 63;
  int ct = r >> 4, st = r & 15;
  int c0 = ct * 64, s0 = st * 64;
  int b = bg >> 4, g = bg & 15;
  int t = threadIdx.x, lane = t & 63, w = t >> 6;
  const float* src = p2 + (size_t)b * D2_ * GS_ + (size_t)g * S_ + s0 + lane;
  #pragma unroll
  for (int i = 0; i < 16; i++) {
    int row = w * 16 + i;
    tl[row][lane] = src[(size_t)(c0 + row) * GS_];
  }
  __syncthreads();
  int cp = t & 31, sr = t >> 5;
  #pragma unroll
  for (int i = 0; i < 8; i++) {
    int sl = sr * 8 + i;
    u32 v = h2bits(__floats2half2_rn(tl[2 * cp][sl], tl[2 * cp + 1][sl]));
    *(u32*)(p2T + (((size_t)bg * 1024 + s0 + sl) * 256 + c0 + 2 * cp)) = v;
  }
}

// ---------------- kNN ----------------
__launch_bounds__(256)
__global__ void knn_kernel(const float* __restrict__ xyz1, const float4* __restrict__ xyz2p,
                           float4* __restrict__ knnw, int4* __restrict__ knni)
{
  int bx = blockIdx.x;
  int bg = bx >> 4;
  int b = bg >> 4, g = bg & 15;
  int n = (bx & 15) * 256 + threadIdx.x;
  const float* x1b = xyz1 + (size_t)b * 3 * GN_ + (size_t)g * N_ + n;
  float x = x1b[0], y = x1b[GN_], z = x1b[2 * GN_];
  const float4* xp = xyz2p + (size_t)bg * 1024;
  float d0 = 3.4e38f, d1 = 3.4e38f, d2 = 3.4e38f;
  int i0 = 0, i1 = 0, i2 = 0;
  for (int q = 0; q < 256; q++) {
    float4 X = xp[q * 4 + 0], Y = xp[q * 4 + 1], Z = xp[q * 4 + 2], M = xp[q * 4 + 3];
    const float* Xa = (const float*)&X;
    const float* Ya = (const float*)&Y;
    const float* Za = (const float*)&Z;
    const float* Ma = (const float*)&M;
    #pragma unroll
    for (int u = 0; u < 4; u++) {
      float cr = x * Xa[u];
      cr = fmaf(y, Ya[u], cr);
      cr = fmaf(z, Za[u], cr);
      float d = fmaf(-2.f, cr, Ma[u]);
      int s = q * 4 + u;
      bool c2 = d < d2, c1 = d < d1, c0 = d < d0;
      d2 = c1 ? d1 : (c2 ? d : d2);  i2 = c1 ? i1 : (c2 ? s : i2);
      d1 = c0 ? d0 : (c1 ? d : d1);  i1 = c0 ? i0 : (c1 ? s : i1);
      d0 = c0 ? d : d0;              i0 = c0 ? s : i0;
    }
  }
  float m1 = x * x + y * y + z * z;
  float t0 = fmaxf(d0 + m1, 0.f), t1 = fmaxf(d1 + m1, 0.f), t2v = fmaxf(d2 + m1, 0.f);
  float w0 = 1.f / (t0 + 1e-8f);
  float w1 = 1.f / (t1 + 1e-8f);
  float w2 = 1.f / (t2v + 1e-8f);
  float inv = 1.f / (w0 + w1 + w2);
  size_t gi = (size_t)bg * 4096 + n;
  knnw[gi] = make_float4(w0 * inv, w1 * inv, w2 * inv, 0.f);
  knni[gi] = make_int4(i0, i1, i2, 0);
}

// ================= GEMM1: 512 thr, M=256 x N=256 (4 tiles of 64n), f16 MFMA ==============
// LDS: Bbuf0 @0 (49152 = 64 rows * 768B, XOR ((r&15)<<4))
//      Bbuf1 @49152 ; outLDS @98304 (64n * 512B, XOR ((n&7)<<4)) ; total 131072
__launch_bounds__(512, 2)
__global__ void gemm1_kernel(const u16* __restrict__ W1h, const float* __restrict__ points1,
                             const u16* __restrict__ p2T,
                             const float4* __restrict__ knnw, const int4* __restrict__ knni,
                             const float* __restrict__ bias,
                             float* __restrict__ sumw, float* __restrict__ sqw,
                             u16* __restrict__ Y1)
{
  __shared__ __align__(16) char smem[131072];
  int bx = blockIdx.x;
  int bg = bx >> 4, ng = bx & 15;
  int b = bg >> 4, g = bg & 15;
  int nbase = ng * 256;
  int t = threadIdx.x, wid = t >> 6, l = t & 63;
  int llo = l & 15, lhi = l >> 4;
  int mw = wid * 32;

  // A fragments in registers (full K)
  f16x8 af[2][12];
  #pragma unroll
  for (int i = 0; i < 2; i++)
    #pragma unroll
    for (int ks = 0; ks < 12; ks++)
      af[i][ks] = *(const f16x8*)(W1h + (size_t)(mw + i * 16 + llo) * 384 + ks * 32 + lhi * 8);

  float bv[2][4];
  #pragma unroll
  for (int i = 0; i < 2; i++)
    #pragma unroll
    for (int r = 0; r < 4; r++)
      bv[i][r] = bias[mw + i * 16 + lhi * 4 + r];

  // staging regs (T14)
  int half = l >> 5, cl = l & 31;
  int hw = wid * 2 + half;               // 0..15, owns rows hw*4..hw*4+3
  const u16* p2b = p2T + (size_t)bg * 1024 * 256;
  uint4 q0[4], q1[4], q2[4];
  __half2 wh[4][3];
  float p1v[16];

  auto issue = [&](int tile) {
    size_t kb = (size_t)bg * 4096 + nbase + tile * 64;
    #pragma unroll
    for (int p = 0; p < 4; p++) {
      int r = hw * 4 + p;
      float4 w4 = knnw[kb + r];
      int4 iv = knni[kb + r];
      wh[p][0] = __half2half2(__float2half_rn(w4.x));
      wh[p][1] = __half2half2(__float2half_rn(w4.y));
      wh[p][2] = __half2half2(__float2half_rn(w4.z));
      q0[p] = *(const uint4*)(p2b + (size_t)iv.x * 256 + cl * 8);
      q1[p] = *(const uint4*)(p2b + (size_t)iv.y * 256 + cl * 8);
      q2[p] = *(const uint4*)(p2b + (size_t)iv.z * 256 + cl * 8);
    }
    const float* p1c = points1 + (size_t)b * 128 * GN_ + (size_t)g * N_ + nbase + tile * 64 + l;
    #pragma unroll
    for (int cp = 0; cp < 16; cp++)
      p1v[cp] = p1c[(size_t)(wid * 16 + cp) * GN_];
  };

  auto writeB = [&](int tile) {
    char* buf = smem + (tile & 1) * 49152;
    #pragma unroll
    for (int p = 0; p < 4; p++) {
      int r = hw * 4 + p;
      const u32* a0 = (const u32*)&q0[p];
      const u32* a1 = (const u32*)&q1[p];
      const u32* a2 = (const u32*)&q2[p];
      uint4 o;
      u32* ow = (u32*)&o;
      #pragma unroll
      for (int w = 0; w < 4; w++) {
        __half2 v = __hmul2(wh[p][2], bits2h(a2[w]));
        v = __hfma2(wh[p][1], bits2h(a1[w]), v);
        v = __hfma2(wh[p][0], bits2h(a0[w]), v);
        ow[w] = h2bits(v);
      }
      int byteoff = r * 768 + ((256 + cl * 16) ^ ((r & 15) << 4));
      *(uint4*)(buf + byteoff) = o;
    }
    #pragma unroll
    for (int cp = 0; cp < 8; cp++) {
      int c = wid * 16 + cp * 2;
      u32 pk = h2bits(__floats2half2_rn(p1v[cp * 2], p1v[cp * 2 + 1]));
      int byteoff = l * 768 + ((c * 2) ^ ((l & 15) << 4));
      *(u32*)(buf + byteoff) = pk;
    }
  };

  float st[2][4], sq2r[2][4];
  #pragma unroll
  for (int i = 0; i < 2; i++)
    #pragma unroll
    for (int r = 0; r < 4; r++) { st[i][r] = 0.f; sq2r[i][r] = 0.f; }

  issue(0);
  writeB(0);
  issue(1);

  for (int t4 = 0; t4 < 4; t4++) {
    __syncthreads();   // B[t4] ready
    const char* buf = smem + (t4 & 1) * 49152;
    f32x4 acc[2][4];
    #pragma unroll
    for (int i = 0; i < 2; i++)
      #pragma unroll
      for (int j = 0; j < 4; j++) acc[i][j] = (f32x4)0.f;
    #pragma unroll
    for (int ks = 0; ks < 12; ks++) {
      f16x8 bfr[4];
      #pragma unroll
      for (int j = 0; j < 4; j++) {
        int rb = j * 16 + llo;
        bfr[j] = *(const f16x8*)(buf + rb * 768 + ((ks * 64 + lhi * 16) ^ ((rb & 15) << 4)));
      }
      #pragma unroll
      for (int i = 0; i < 2; i++)
        #pragma unroll
        for (int j = 0; j < 4; j++)
          acc[i][j] = __builtin_amdgcn_mfma_f32_16x16x32_f16(af[i][ks], bfr[j], acc[i][j], 0, 0, 0);
    }
    if (t4 < 3) writeB(t4 + 1);
    // epilogue: bias, stats, outLDS (64 n x 512B)
    #pragma unroll
    for (int i = 0; i < 2; i++) {
      int mloc = mw + i * 16 + lhi * 4;
      int slotb = (mloc * 2) & ~15, off8 = (mloc * 2) & 15;
      #pragma unroll
      for (int j = 0; j < 4; j++) {
        int n = j * 16 + llo;
        float v0 = acc[i][j][0] + bv[i][0];
        float v1 = acc[i][j][1] + bv[i][1];
        float v2 = acc[i][j][2] + bv[i][2];
        float v3 = acc[i][j][3] + bv[i][3];
        st[i][0] += v0; sq2r[i][0] += v0 * v0;
        st[i][1] += v1; sq2r[i][1] += v1 * v1;
        st[i][2] += v2; sq2r[i][2] += v2 * v2;
        st[i][3] += v3; sq2r[i][3] += v3 * v3;
        int base = n * 512 + (slotb ^ ((n & 7) << 4)) + off8;
        *(u32*)(smem + 98304 + base) = h2bits(__floats2half2_rn(v0, v1));
        *(u32*)(smem + 98304 + base + 4) = h2bits(__floats2half2_rn(v2, v3));
      }
    }
    __syncthreads();   // outLDS + writeB(t4+1) done
    {
      int rn = t >> 3, cq = t & 7;
      u16* yrow = Y1 + ((size_t)bg * 4096 + nbase + t4 * 64 + rn) * 256;
      #pragma unroll
      for (int u = 0; u < 4; u++) {
        int s = cq * 4 + u;
        uint4 v = *(const uint4*)(smem + 98304 + rn * 512 + ((s * 16) ^ ((rn & 7) << 4)));
        *(uint4*)(yrow + s * 8) = v;
      }
    }
    if (t4 < 2) issue(t4 + 2);
  }

  #pragma unroll
  for (int i = 0; i < 2; i++)
    #pragma unroll
    for (int r = 0; r < 4; r++) {
      float s = st[i][r], ss = sq2r[i][r];
      #pragma unroll
      for (int off = 1; off < 16; off <<= 1) {
        s += __shfl_xor(s, off, 64);
        ss += __shfl_xor(ss, off, 64);
      }
      if (llo == 0) {
        int m = mw + i * 16 + lhi * 4 + r;
        atomicAdd(&sumw[g * 256 + m], s);
        atomicAdd(&sqw[g * 256 + m], ss);
      }
    }
}

// ---------------- BN finalize: float2 and/or packed half2 ----------------
__global__ void bnfin_kernel(const float* __restrict__ sum, const float* __restrict__ sq,
                             const float* __restrict__ gamma, const float* __restrict__ beta,
                             float2* __restrict__ ss, u32* __restrict__ scpk, u32* __restrict__ shpk)
{
  __shared__ float scl[256], shl[256];
  int g = blockIdx.x, m = threadIdx.x;
  int i = g * 256 + m;
  float mean = sum[i] * (1.f / 8192.f);
  float var = sq[i] * (1.f / 8192.f) - mean * mean;
  var = fmaxf(var, 0.f);
  float rstd = rsqrtf(var + 1e-5f);
  float sc = gamma[m] * rstd;
  float sh = beta[m] - mean * sc;
  if (ss) ss[i] = make_float2(sc, sh);
  if (scpk) {
    scl[m] = sc; shl[m] = sh;
    __syncthreads();
    if (m < 128) {
      scpk[g * 128 + m] = h2bits(__floats2half2_rn(scl[2 * m], scl[2 * m + 1]));
      shpk[g * 128 + m] = h2bits(__floats2half2_rn(shl[2 * m], shl[2 * m + 1]));
    }
  }
}

// ================= GEMM2: 512 thr, M=256 x N=256, B = relu(bn1(Y1)) f16 ==============
// LDS: Bbuf0 @0 (32768 = 64 rows * 512B, XOR ((r&15)<<4)); Bbuf1 @32768
//      outLDS @65536 (256 m * 128B, XOR ((m&7)<<4)); params @98304 (1KB sc + 1KB sh... 256 u32 x2)
__launch_bounds__(512, 2)
__global__ void gemm2_kernel(const u16* __restrict__ W2h, const u16* __restrict__ Y1,
                             const u32* __restrict__ scpk, const u32* __restrict__ shpk,
                             const float* __restrict__ bias,
                             float* __restrict__ sumw, float* __restrict__ sqw,
                             u16* __restrict__ Y2)
{
  __shared__ __align__(16) char smem[99328];
  int bx = blockIdx.x;
  int bg = bx >> 4, ng = bx & 15;
  int b = bg >> 4, g = bg & 15;
  int nbase = ng * 256;
  int t = threadIdx.x, wid = t >> 6, l = t & 63;
  int llo = l & 15, lhi = l >> 4;
  int mw = wid * 32;

  f16x8 af[2][8];
  #pragma unroll
  for (int i = 0; i < 2; i++)
    #pragma unroll
    for (int ks = 0; ks < 8; ks++)
      af[i][ks] = *(const f16x8*)(W2h + (size_t)(mw + i * 16 + llo) * 256 + ks * 32 + lhi * 8);

  float bv[2][4];
  #pragma unroll
  for (int i = 0; i < 2; i++)
    #pragma unroll
    for (int r = 0; r < 4; r++)
      bv[i][r] = bias[mw + i * 16 + lhi * 4 + r];

  if (t < 128) {
    *(u32*)(smem + 98304 + t * 4) = scpk[g * 128 + t];
    *(u32*)(smem + 98816 + t * 4) = shpk[g * 128 + t];
  }

  int rn = t >> 3, qq = t & 7;
  uint4 sreg[4];
  auto issue = [&](int tile) {
    const u16* yrow = Y1 + ((size_t)bg * 4096 + nbase + tile * 64 + rn) * 256;
    #pragma unroll
    for (int u = 0; u < 4; u++)
      sreg[u] = *(const uint4*)(yrow + (qq * 4 + u) * 8);
  };
  auto writeB = [&](int tile) {
    char* buf = smem + (tile & 1) * 32768;
    const u32* scp = (const u32*)(smem + 98304);
    const u32* shp = (const u32*)(smem + 98816);
    #pragma unroll
    for (int u = 0; u < 4; u++) {
      int s = qq * 4 + u;
      const u32* yw = (const u32*)&sreg[u];
      uint4 o;
      u32* ow = (u32*)&o;
      #pragma unroll
      for (int w = 0; w < 4; w++) {
        int pairi = s * 4 + w;
        __half2 v = __hfma2(bits2h(yw[w]), bits2h(scp[pairi]), bits2h(shp[pairi]));
        ow[w] = pkmax0(h2bits(v));
      }
      *(uint4*)(buf + rn * 512 + ((s * 16) ^ ((rn & 15) << 4))) = o;
    }
  };

  float st[2][4], sq2r[2][4];
  #pragma unroll
  for (int i = 0; i < 2; i++)
    #pragma unroll
    for (int r = 0; r < 4; r++) { st[i][r] = 0.f; sq2r[i][r] = 0.f; }

  issue(0);
  __syncthreads();   // params ready
  writeB(0);
  issue(1);

  for (int t4 = 0; t4 < 4; t4++) {
    __syncthreads();   // B[t4] ready
    const char* buf = smem + (t4 & 1) * 32768;
    f32x4 acc[2][4];
    #pragma unroll
    for (int i = 0; i < 2; i++)
      #pragma unroll
      for (int j = 0; j < 4; j++) acc[i][j] = (f32x4)0.f;
    #pragma unroll
    for (int ks = 0; ks < 8; ks++) {
      f16x8 bfr[4];
      #pragma unroll
      for (int j = 0; j < 4; j++) {
        int rb = j * 16 + llo;
        bfr[j] = *(const f16x8*)(buf + rb * 512 + ((ks * 64 + lhi * 16) ^ ((rb & 15) << 4)));
      }
      #pragma unroll
      for (int i = 0; i < 2; i++)
        #pragma unroll
        for (int j = 0; j < 4; j++)
          acc[i][j] = __builtin_amdgcn_mfma_f32_16x16x32_f16(af[i][ks], bfr[j], acc[i][j], 0, 0, 0);
    }
    if (t4 < 3) writeB(t4 + 1);
    // epilogue: bias, stats, m-major outLDS (256 m x 128B)
    #pragma unroll
    for (int i = 0; i < 2; i++) {
      #pragma unroll
      for (int j = 0; j < 4; j++) {
        int n = j * 16 + llo;
        int slotn = (n >> 3) * 16, offn = (n * 2) & 15;
        #pragma unroll
        for (int r = 0; r < 4; r++) {
          float v = acc[i][j][r] + bv[i][r];
          st[i][r] += v; sq2r[i][r] += v * v;
          int mr = mw + i * 16 + lhi * 4 + r;
          *(u16*)(smem + 65536 + mr * 128 + (slotn ^ ((mr & 7) << 4)) + offn) =
              __half_as_ushort(__float2half_rn(v));
        }
      }
    }
    __syncthreads();   // outLDS + writeB done
    {
      int mr = t >> 1, hh = t & 1;
      u16* yrow = Y2 + ((size_t)b * 256 + mr) * (size_t)GN_ + (size_t)g * N_ + nbase + t4 * 64;
      #pragma unroll
      for (int u = 0; u < 4; u++) {
        int s = hh * 4 + u;
        uint4 v = *(const uint4*)(smem + 65536 + mr * 128 + ((s * 16) ^ ((mr & 7) << 4)));
        *(uint4*)(yrow + s * 8) = v;
      }
    }
    if (t4 < 2) issue(t4 + 2);
  }

  #pragma unroll
  for (int i = 0; i < 2; i++)
    #pragma unroll
    for (int r = 0; r < 4; r++) {
      float s = st[i][r], ss = sq2r[i][r];
      #pragma unroll
      for (int off = 1; off < 16; off <<= 1) {
        s += __shfl_xor(s, off, 64);
        ss += __shfl_xor(ss, off, 64);
      }
      if (llo == 0) {
        int m = mw + i * 16 + lhi * 4 + r;
        atomicAdd(&sumw[g * 256 + m], s);
        atomicAdd(&sqw[g * 256 + m], ss);
      }
    }
}

// ---------------- BN apply 2: Out = relu(bn2(Y2)), f16 -> f32 ----------------
__launch_bounds__(256)
__global__ void bnapply2_kernel(const u16* __restrict__ Y2, const float2* __restrict__ ss,
                                float* __restrict__ Out)
{
  int f8 = blockIdx.x * 256 + threadIdx.x;
  size_t base = (size_t)f8 * 8;
  int m = (int)((base >> 16) & 255);
  int g = (int)((base >> 12) & 15);
  float2 sc = ss[g * 256 + m];
  uint4 yv = *(const uint4*)(Y2 + base);
  const u32* yw = (const u32*)&yv;
  float4 a, b4;
  float* av = (float*)&a;
  float* bvv = (float*)&b4;
  #pragma unroll
  for (int i = 0; i < 2; i++) {
    float2 f = __half22float2(bits2h(yw[i]));
    av[2 * i]     = fmaxf(fmaf(f.x, sc.x, sc.y), 0.f);
    av[2 * i + 1] = fmaxf(fmaf(f.y, sc.x, sc.y), 0.f);
  }
  #pragma unroll
  for (int i = 0; i < 2; i++) {
    float2 f = __half22float2(bits2h(yw[2 + i]));
    bvv[2 * i]     = fmaxf(fmaf(f.x, sc.x, sc.y), 0.f);
    bvv[2 * i + 1] = fmaxf(fmaf(f.y, sc.x, sc.y), 0.f);
  }
  *(float4*)(Out + base) = a;
  *(float4*)(Out + base + 4) = b4;
}

// ---------------- launch ----------------
extern "C" void kernel_launch(void* const* d_in, const int* in_sizes, int n_in,
                              void* d_out, int out_size, void* d_ws, size_t ws_size,
                              hipStream_t stream)
{
  (void)in_sizes; (void)n_in; (void)out_size; (void)ws_size;
  const float* xyz1    = (const float*)d_in[0];
  const float* points1 = (const float*)d_in[1];
  const float* xyz2    = (const float*)d_in[3];
  const float* points2 = (const float*)d_in[4];
  const float* W1      = (const float*)d_in[6];
  const float* b1      = (const float*)d_in[7];
  const float* gamma1  = (const float*)d_in[8];
  const float* beta1   = (const float*)d_in[9];
  const float* W2      = (const float*)d_in[10];
  const float* b2      = (const float*)d_in[11];
  const float* gamma2  = (const float*)d_in[12];
  const float* beta2   = (const float*)d_in[13];
  float* out = (float*)d_out;
  char* ws = (char*)d_ws;

  u16*    W1h   = (u16*)(ws + OFF_W1H);
  u16*    W2h   = (u16*)(ws + OFF_W2H);
  float4* xyz2p = (float4*)(ws + OFF_XYZ2P);
  float*  sum1  = (float*)(ws + OFF_SUM1);
  float*  sq1   = (float*)(ws + OFF_SQ1);
  float*  sum2  = (float*)(ws + OFF_SUM2);
  float*  sq2   = (float*)(ws + OFF_SQ2);
  u32*    scpk1 = (u32*)(ws + OFF_SCPK1);
  u32*    shpk1 = (u32*)(ws + OFF_SHPK1);
  float2* ss2   = (float2*)(ws + OFF_SS2);
  float4* knnw  = (float4*)(ws + OFF_KNNW);
  int4*   knni  = (int4*)(ws + OFF_KNNI);
  u16*    p2T   = (u16*)(ws + OFF_P2T);
  u16*    Y2    = (u16*)(ws + OFF_Y2);
  u16*    Y1    = (u16*)(ws + OFF_Y1);

  prep_kernel<<<736, 256, 0, stream>>>(W1, W2, xyz2, W1h, W2h, xyz2p, sum1);
  t2_kernel<<<2048, 256, 0, stream>>>(points2, p2T);
  knn_kernel<<<512, 256, 0, stream>>>(xyz1, xyz2p, knnw, knni);
  gemm1_kernel<<<512, 512, 0, stream>>>(W1h, points1, p2T, knnw, knni, b1, sum1, sq1, Y1);
  bnfin_kernel<<<16, 256, 0, stream>>>(sum1, sq1, gamma1, beta1, nullptr, scpk1, shpk1);
  gemm2_kernel<<<512, 512, 0, stream>>>(W2h, Y1, scpk1, shpk1, b2, sum2, sq2, Y2);
  bnfin_kernel<<<16, 256, 0, stream>>>(sum2, sq2, gamma2, beta2, ss2, nullptr, nullptr);
  bnapply2_kernel<<<16384, 256, 0, stream>>>(Y2, ss2, out);
}

// Round 5
// 321.081 us; speedup vs baseline: 1.1796x; 1.1796x over previous
//
#include <hip/hip_runtime.h>
#include <hip/hip_bf16.h>
#include <hip/hip_fp16.h>

// Problem constants
#define B_    2
#define G_    16
#define N_    4096
#define S_    1024
#define D1_   128
#define D2_   256
#define CIN_  384
#define BG_   32
#define GN_   65536
#define GS_   16384

typedef unsigned int u32;
typedef unsigned short u16;
typedef _Float16 f16x8 __attribute__((ext_vector_type(8)));
typedef float f32x4 __attribute__((ext_vector_type(4)));

__device__ __forceinline__ u32 h2bits(__half2 h) { union { __half2 h; u32 u; } c; c.h = h; return c.u; }
__device__ __forceinline__ __half2 bits2h(u32 u) { union { __half2 h; u32 u; } c; c.u = u; return c.h; }
__device__ __forceinline__ u32 pkmax0(u32 v) {
  u32 r; asm("v_pk_max_f16 %0, %1, %2" : "=v"(r) : "v"(v), "v"(0)); return r;
}
__device__ __forceinline__ void g2l16(const u16* g, u16* l) {
  __builtin_amdgcn_global_load_lds((const __attribute__((address_space(1))) u32*)g,
                                   (__attribute__((address_space(3))) u32*)l, 16, 0, 0);
}

// ---------------- workspace layout (bytes) ----------------
#define OFF_W1H    0u           // 256*384*2
#define OFF_W2H    196608u      // 256*256*2
#define OFF_XYZ2P  327680u      // 32*256*4*16
#define OFF_SUM1   851968u      // 4 x 16KB contiguous (sum1,sq1,sum2,sq2)
#define OFF_SQ1    868352u
#define OFF_SUM2   884736u
#define OFF_SQ2    901120u
#define OFF_SCPK1  917504u      // 16*128*4 packed half2 scale (BN1)
#define OFF_SHPK1  925696u      // packed half2 shift (BN1)
#define OFF_SS2    950272u      // float2 (BN2)
#define OFF_KNNP   983040u      // 32*4096*16 packed knn records
#define OFF_P2T    5177344u     // 32*1024*256*2 f16
#define OFF_Y2     21954560u    // f16 pre-BN2, OUT layout [b][m][gn]
#define OFF_Y1     122617856u   // f16 pre-BN1, [bg*4096+n][256]

// ---------------- prep: weights->f16, zero stats, pack xyz2 ----------------
__launch_bounds__(256)
__global__ void prep_kernel(const float* __restrict__ W1, const float* __restrict__ W2,
                            const float* __restrict__ xyz2,
                            u16* __restrict__ W1h, u16* __restrict__ W2h,
                            float4* __restrict__ xyz2p, float* __restrict__ zeros)
{
  int idx = blockIdx.x * 256 + threadIdx.x;
  if (idx < 98304) { W1h[idx] = __half_as_ushort(__float2half_rn(W1[idx])); return; }
  idx -= 98304;
  if (idx < 65536) { W2h[idx] = __half_as_ushort(__float2half_rn(W2[idx])); return; }
  idx -= 65536;
  if (idx < 16384) { zeros[idx] = 0.f; return; }
  idx -= 16384;
  int bg = idx >> 8, q = idx & 255;
  int b = bg >> 4, g = bg & 15;
  const float* base = xyz2 + (size_t)b * 3 * GS_ + (size_t)g * S_ + q * 4;
  float4 X = *(const float4*)(base);
  float4 Y = *(const float4*)(base + GS_);
  float4 Z = *(const float4*)(base + 2 * GS_);
  float4 M;
  M.x = X.x*X.x + Y.x*Y.x + Z.x*Z.x;
  M.y = X.y*X.y + Y.y*Y.y + Z.y*Z.y;
  M.z = X.z*X.z + Y.z*Y.z + Z.z*Z.z;
  M.w = X.w*X.w + Y.w*Y.w + Z.w*Z.w;
  float4* dst = xyz2p + (size_t)idx * 4;
  dst[0] = X; dst[1] = Y; dst[2] = Z; dst[3] = M;
}

// ---------------- transpose points2 -> p2T [s][256] f16 ----------------
__launch_bounds__(256)
__global__ void t2_kernel(const float* __restrict__ p2, u16* __restrict__ p2T)
{
  __shared__ float tl[64][65];
  int bx = blockIdx.x;
  int bg = bx >> 6, r = bx & 63;
  int ct = r >> 4, st = r & 15;
  int c0 = ct * 64, s0 = st * 64;
  int b = bg >> 4, g = bg & 15;
  int t = threadIdx.x, lane = t & 63, w = t >> 6;
  const float* src = p2 + (size_t)b * D2_ * GS_ + (size_t)g * S_ + s0 + lane;
  #pragma unroll
  for (int i = 0; i < 16; i++) {
    int row = w * 16 + i;
    tl[row][lane] = src[(size_t)(c0 + row) * GS_];
  }
  __syncthreads();
  int cp = t & 31, sr = t >> 5;
  #pragma unroll
  for (int i = 0; i < 8; i++) {
    int sl = sr * 8 + i;
    u32 v = h2bits(__floats2half2_rn(tl[2 * cp][sl], tl[2 * cp + 1][sl]));
    *(u32*)(p2T + (((size_t)bg * 1024 + s0 + sl) * 256 + c0 + 2 * cp)) = v;
  }
}

// ---------------- kNN -> packed record {h w0,w1,w2 ; u16 i0,i1,i2} ----------------
__launch_bounds__(256)
__global__ void knn_kernel(const float* __restrict__ xyz1, const float4* __restrict__ xyz2p,
                           uint4* __restrict__ knnp)
{
  int bx = blockIdx.x;
  int bg = bx >> 4;
  int b = bg >> 4, g = bg & 15;
  int n = (bx & 15) * 256 + threadIdx.x;
  const float* x1b = xyz1 + (size_t)b * 3 * GN_ + (size_t)g * N_ + n;
  float x = x1b[0], y = x1b[GN_], z = x1b[2 * GN_];
  const float4* xp = xyz2p + (size_t)bg * 1024;
  float d0 = 3.4e38f, d1 = 3.4e38f, d2 = 3.4e38f;
  int i0 = 0, i1 = 0, i2 = 0;
  for (int q = 0; q < 256; q++) {
    float4 X = xp[q * 4 + 0], Y = xp[q * 4 + 1], Z = xp[q * 4 + 2], M = xp[q * 4 + 3];
    const float* Xa = (const float*)&X;
    const float* Ya = (const float*)&Y;
    const float* Za = (const float*)&Z;
    const float* Ma = (const float*)&M;
    #pragma unroll
    for (int u = 0; u < 4; u++) {
      float cr = x * Xa[u];
      cr = fmaf(y, Ya[u], cr);
      cr = fmaf(z, Za[u], cr);
      float d = fmaf(-2.f, cr, Ma[u]);
      int s = q * 4 + u;
      bool c2 = d < d2, c1 = d < d1, c0 = d < d0;
      d2 = c1 ? d1 : (c2 ? d : d2);  i2 = c1 ? i1 : (c2 ? s : i2);
      d1 = c0 ? d0 : (c1 ? d : d1);  i1 = c0 ? i0 : (c1 ? s : i1);
      d0 = c0 ? d : d0;              i0 = c0 ? s : i0;
    }
  }
  float m1 = x * x + y * y + z * z;
  float t0 = fmaxf(d0 + m1, 0.f), t1 = fmaxf(d1 + m1, 0.f), t2v = fmaxf(d2 + m1, 0.f);
  float w0 = 1.f / (t0 + 1e-8f);
  float w1 = 1.f / (t1 + 1e-8f);
  float w2 = 1.f / (t2v + 1e-8f);
  float inv = 1.f / (w0 + w1 + w2);
  uint4 rec;
  rec.x = h2bits(__floats2half2_rn(w0 * inv, w1 * inv));
  rec.y = (u32)__half_as_ushort(__float2half_rn(w2 * inv));
  rec.z = (u32)i0 | ((u32)i1 << 16);
  rec.w = (u32)i2;
  knnp[(size_t)bg * 4096 + n] = rec;
}

// ================= GEMM1: 256 thr, M=256 x N=64, wave=64m x 64n, K=384 =================
// LDS: B 64 x 768B XOR((r&15)<<4) @0 (49152); A dbuf 2x16384 @49152; out 64x512B @49152 (reuse)
// total 81920 -> exactly 2 blocks/CU.
__launch_bounds__(256, 2)
__global__ void gemm1_kernel(const u16* __restrict__ W1h, const float* __restrict__ points1,
                             const u16* __restrict__ p2T, const uint4* __restrict__ knnp,
                             const float* __restrict__ bias,
                             float* __restrict__ sumw, float* __restrict__ sqw,
                             u16* __restrict__ Y1)
{
  __shared__ __align__(16) char smem[81920];
  int bx = blockIdx.x;
  int bg = bx >> 6, nt = bx & 63;
  int b = bg >> 4, g = bg & 15;
  int n0 = nt * 64;
  int t = threadIdx.x, wid = t >> 6, l = t & 63;
  int llo = l & 15, lhi = l >> 4;

  // ---- B-build: interp ch 128..383 (f16 pk), 8 rows/thread ----
  {
    int half = l >> 5, cl = l & 31;
    size_t kb = (size_t)bg * 4096 + n0;
    const u16* p2b = p2T + (size_t)bg * 1024 * 256;
    #pragma unroll
    for (int p = 0; p < 8; p++) {
      int r = wid * 16 + p * 2 + half;
      uint4 kp = knnp[kb + r];
      __half2 w0 = __half2half2(__low2half(bits2h(kp.x)));
      __half2 w1 = __half2half2(__high2half(bits2h(kp.x)));
      __half2 w2 = __half2half2(__low2half(bits2h(kp.y)));
      int i0 = kp.z & 0xffff, i1 = kp.z >> 16, i2 = kp.w & 0xffff;
      uint4 q0 = *(const uint4*)(p2b + (size_t)i0 * 256 + cl * 8);
      uint4 q1 = *(const uint4*)(p2b + (size_t)i1 * 256 + cl * 8);
      uint4 q2 = *(const uint4*)(p2b + (size_t)i2 * 256 + cl * 8);
      const u32* a0 = (const u32*)&q0;
      const u32* a1 = (const u32*)&q1;
      const u32* a2 = (const u32*)&q2;
      uint4 o;
      u32* ow = (u32*)&o;
      #pragma unroll
      for (int w = 0; w < 4; w++) {
        __half2 v = __hmul2(w2, bits2h(a2[w]));
        v = __hfma2(w1, bits2h(a1[w]), v);
        v = __hfma2(w0, bits2h(a0[w]), v);
        ow[w] = h2bits(v);
      }
      *(uint4*)(smem + r * 768 + ((256 + cl * 16) ^ ((r & 15) << 4))) = o;
    }
    // p1 ch 0..127 transpose: thread owns row l, 32 channels
    const float* p1c = points1 + ((size_t)b * 128 + wid * 32) * (size_t)GN_
                     + (size_t)g * N_ + n0 + l;
    #pragma unroll
    for (int cp = 0; cp < 16; cp++) {
      int c = wid * 32 + cp * 2;
      u32 pk = h2bits(__floats2half2_rn(p1c[(size_t)(cp * 2) * GN_],
                                        p1c[(size_t)(cp * 2 + 1) * GN_]));
      *(u32*)(smem + l * 768 + ((c * 2) ^ ((l & 15) << 4))) = pk;
    }
  }

  // ---- A staging: linear [m][64B], per-K-step 16KB, conflict-free reads ----
  auto stageA = [&](int ks) {
    u16* dst = (u16*)(smem + 49152 + (ks & 1) * 16384);
    #pragma unroll
    for (int q = 0; q < 4; q++) {
      int idx = q * 256 + t;
      g2l16(W1h + (size_t)(idx >> 2) * 384 + ks * 32 + (idx & 3) * 8,
            dst + (q * 256 + wid * 64) * 8);
    }
  };

  stageA(0);
  __syncthreads();   // B built + A0 landed

  f32x4 acc[4][4];
  #pragma unroll
  for (int i = 0; i < 4; i++)
    #pragma unroll
    for (int j = 0; j < 4; j++) acc[i][j] = (f32x4)0.f;

  for (int ks = 0; ks < 12; ks++) {
    if (ks < 11) stageA(ks + 1);
    const char* Ab = smem + 49152 + (ks & 1) * 16384;
    f16x8 bfr[4], afr[4];
    #pragma unroll
    for (int j = 0; j < 4; j++) {
      int rb = j * 16 + llo;
      bfr[j] = *(const f16x8*)(smem + rb * 768 + ((ks * 64 + lhi * 16) ^ ((rb & 15) << 4)));
    }
    #pragma unroll
    for (int i = 0; i < 4; i++)
      afr[i] = *(const f16x8*)(Ab + (wid * 64 + i * 16 + llo) * 64 + lhi * 16);
    #pragma unroll
    for (int i = 0; i < 4; i++)
      #pragma unroll
      for (int j = 0; j < 4; j++)
        acc[i][j] = __builtin_amdgcn_mfma_f32_16x16x32_f16(afr[i], bfr[j], acc[i][j], 0, 0, 0);
    __syncthreads();   // A[ks+1] landed; everyone done with buf[ks] and B-reads of this ks
  }

  // ---- epilogue: bias + stats + n-major out-LDS (reuses A region) ----
  #pragma unroll
  for (int i = 0; i < 4; i++) {
    int mloc = wid * 64 + i * 16 + lhi * 4;
    float b0 = bias[mloc], b1 = bias[mloc + 1], b2 = bias[mloc + 2], b3 = bias[mloc + 3];
    float s0 = 0, s1 = 0, s2 = 0, s3 = 0, q0 = 0, q1 = 0, q2 = 0, q3 = 0;
    int slotb = (mloc * 2) & ~15, off8 = (mloc * 2) & 15;
    #pragma unroll
    for (int j = 0; j < 4; j++) {
      int n = j * 16 + llo;
      float v0 = acc[i][j][0] + b0;
      float v1 = acc[i][j][1] + b1;
      float v2 = acc[i][j][2] + b2;
      float v3 = acc[i][j][3] + b3;
      s0 += v0; q0 += v0 * v0;
      s1 += v1; q1 += v1 * v1;
      s2 += v2; q2 += v2 * v2;
      s3 += v3; q3 += v3 * v3;
      int base = n * 512 + (slotb ^ ((n & 7) << 4)) + off8;
      *(u32*)(smem + 49152 + base) = h2bits(__floats2half2_rn(v0, v1));
      *(u32*)(smem + 49152 + base + 4) = h2bits(__floats2half2_rn(v2, v3));
    }
    #pragma unroll
    for (int off = 1; off < 16; off <<= 1) {
      s0 += __shfl_xor(s0, off, 64); q0 += __shfl_xor(q0, off, 64);
      s1 += __shfl_xor(s1, off, 64); q1 += __shfl_xor(q1, off, 64);
      s2 += __shfl_xor(s2, off, 64); q2 += __shfl_xor(q2, off, 64);
      s3 += __shfl_xor(s3, off, 64); q3 += __shfl_xor(q3, off, 64);
    }
    if (llo == 0) {
      atomicAdd(&sumw[g * 256 + mloc], s0);     atomicAdd(&sqw[g * 256 + mloc], q0);
      atomicAdd(&sumw[g * 256 + mloc + 1], s1); atomicAdd(&sqw[g * 256 + mloc + 1], q1);
      atomicAdd(&sumw[g * 256 + mloc + 2], s2); atomicAdd(&sqw[g * 256 + mloc + 2], q2);
      atomicAdd(&sumw[g * 256 + mloc + 3], s3); atomicAdd(&sqw[g * 256 + mloc + 3], q3);
    }
  }
  __syncthreads();
  {
    int rn = t >> 2, cq = t & 3;
    u16* yrow = Y1 + ((size_t)bg * 4096 + n0 + rn) * 256;
    #pragma unroll
    for (int u = 0; u < 8; u++) {
      int s = u * 4 + cq;
      uint4 v = *(const uint4*)(smem + 49152 + rn * 512 + ((s * 16) ^ ((rn & 7) << 4)));
      *(uint4*)(yrow + s * 8) = v;
    }
  }
}

// ---------------- BN finalize ----------------
__global__ void bnfin_kernel(const float* __restrict__ sum, const float* __restrict__ sq,
                             const float* __restrict__ gamma, const float* __restrict__ beta,
                             float2* __restrict__ ss, u32* __restrict__ scpk, u32* __restrict__ shpk)
{
  __shared__ float scl[256], shl[256];
  int g = blockIdx.x, m = threadIdx.x;
  int i = g * 256 + m;
  float mean = sum[i] * (1.f / 8192.f);
  float var = sq[i] * (1.f / 8192.f) - mean * mean;
  var = fmaxf(var, 0.f);
  float rstd = rsqrtf(var + 1e-5f);
  float sc = gamma[m] * rstd;
  float sh = beta[m] - mean * sc;
  if (ss) ss[i] = make_float2(sc, sh);
  if (scpk) {
    scl[m] = sc; shl[m] = sh;
    __syncthreads();
    if (m < 128) {
      scpk[g * 128 + m] = h2bits(__floats2half2_rn(scl[2 * m], scl[2 * m + 1]));
      shpk[g * 128 + m] = h2bits(__floats2half2_rn(shl[2 * m], shl[2 * m + 1]));
    }
  }
}

// ================= GEMM2: 256 thr, M=256 x N=64, wave=64m x 64n, K=256 =================
// LDS: B 64 x 512B XOR((r&15)<<4) @0 (32768); A dbuf 2x16384 @32768;
//      out2 256m x 128B @32768 (reuse); params @65536 (1KB). total 66560 -> 2 blocks/CU.
__launch_bounds__(256, 2)
__global__ void gemm2_kernel(const u16* __restrict__ W2h, const u16* __restrict__ Y1,
                             const u32* __restrict__ scpk, const u32* __restrict__ shpk,
                             const float* __restrict__ bias,
                             float* __restrict__ sumw, float* __restrict__ sqw,
                             u16* __restrict__ Y2)
{
  __shared__ __align__(16) char smem[66560];
  int bx = blockIdx.x;
  int bg = bx >> 6, nt = bx & 63;
  int b = bg >> 4, g = bg & 15;
  int n0 = nt * 64;
  int t = threadIdx.x, wid = t >> 6, l = t & 63;
  int llo = l & 15, lhi = l >> 4;

  if (t < 128) {
    *(u32*)(smem + 65536 + t * 4) = scpk[g * 128 + t];
    *(u32*)(smem + 66048 + t * 4) = shpk[g * 128 + t];
  }

  // ---- B-build: relu(bn1(Y1)) f16, rows [n0..n0+64) ----
  {
    int rn = t >> 2, qq = t & 3;
    const u16* yrow = Y1 + ((size_t)bg * 4096 + n0 + rn) * 256 + qq * 64;
    uint4 sreg[8];
    #pragma unroll
    for (int u = 0; u < 8; u++) sreg[u] = *(const uint4*)(yrow + u * 8);
    __syncthreads();   // params visible
    const u32* scp = (const u32*)(smem + 65536);
    const u32* shp = (const u32*)(smem + 66048);
    #pragma unroll
    for (int u = 0; u < 8; u++) {
      int s = qq * 8 + u;
      const u32* yw = (const u32*)&sreg[u];
      uint4 o;
      u32* ow = (u32*)&o;
      #pragma unroll
      for (int w = 0; w < 4; w++) {
        int pairi = qq * 32 + u * 4 + w;
        __half2 v = __hfma2(bits2h(yw[w]), bits2h(scp[pairi]), bits2h(shp[pairi]));
        ow[w] = pkmax0(h2bits(v));
      }
      *(uint4*)(smem + rn * 512 + ((s * 16) ^ ((rn & 15) << 4))) = o;
    }
  }

  auto stageA = [&](int ks) {
    u16* dst = (u16*)(smem + 32768 + (ks & 1) * 16384);
    #pragma unroll
    for (int q = 0; q < 4; q++) {
      int idx = q * 256 + t;
      g2l16(W2h + (size_t)(idx >> 2) * 256 + ks * 32 + (idx & 3) * 8,
            dst + (q * 256 + wid * 64) * 8);
    }
  };

  stageA(0);
  __syncthreads();   // B built + A0 landed

  f32x4 acc[4][4];
  #pragma unroll
  for (int i = 0; i < 4; i++)
    #pragma unroll
    for (int j = 0; j < 4; j++) acc[i][j] = (f32x4)0.f;

  for (int ks = 0; ks < 8; ks++) {
    if (ks < 7) stageA(ks + 1);
    const char* Ab = smem + 32768 + (ks & 1) * 16384;
    f16x8 bfr[4], afr[4];
    #pragma unroll
    for (int j = 0; j < 4; j++) {
      int rb = j * 16 + llo;
      bfr[j] = *(const f16x8*)(smem + rb * 512 + ((ks * 64 + lhi * 16) ^ ((rb & 15) << 4)));
    }
    #pragma unroll
    for (int i = 0; i < 4; i++)
      afr[i] = *(const f16x8*)(Ab + (wid * 64 + i * 16 + llo) * 64 + lhi * 16);
    #pragma unroll
    for (int i = 0; i < 4; i++)
      #pragma unroll
      for (int j = 0; j < 4; j++)
        acc[i][j] = __builtin_amdgcn_mfma_f32_16x16x32_f16(afr[i], bfr[j], acc[i][j], 0, 0, 0);
    __syncthreads();
  }

  // ---- epilogue: bias + stats + m-major out-LDS (256m x 128B, reuses A region) ----
  #pragma unroll
  for (int i = 0; i < 4; i++) {
    int mloc = wid * 64 + i * 16 + lhi * 4;
    float b0 = bias[mloc], b1 = bias[mloc + 1], b2 = bias[mloc + 2], b3 = bias[mloc + 3];
    float s0 = 0, s1 = 0, s2 = 0, s3 = 0, q0 = 0, q1 = 0, q2 = 0, q3 = 0;
    #pragma unroll
    for (int j = 0; j < 4; j++) {
      int n = j * 16 + llo;
      int slotn = (n >> 3) * 16, offn = (n * 2) & 15;
      float v0 = acc[i][j][0] + b0;
      float v1 = acc[i][j][1] + b1;
      float v2 = acc[i][j][2] + b2;
      float v3 = acc[i][j][3] + b3;
      s0 += v0; q0 += v0 * v0;
      s1 += v1; q1 += v1 * v1;
      s2 += v2; q2 += v2 * v2;
      s3 += v3; q3 += v3 * v3;
      *(u16*)(smem + 32768 + (mloc + 0) * 128 + (slotn ^ (((mloc + 0) & 7) << 4)) + offn) =
          __half_as_ushort(__float2half_rn(v0));
      *(u16*)(smem + 32768 + (mloc + 1) * 128 + (slotn ^ (((mloc + 1) & 7) << 4)) + offn) =
          __half_as_ushort(__float2half_rn(v1));
      *(u16*)(smem + 32768 + (mloc + 2) * 128 + (slotn ^ (((mloc + 2) & 7) << 4)) + offn) =
          __half_as_ushort(__float2half_rn(v2));
      *(u16*)(smem + 32768 + (mloc + 3) * 128 + (slotn ^ (((mloc + 3) & 7) << 4)) + offn) =
          __half_as_ushort(__float2half_rn(v3));
    }
    #pragma unroll
    for (int off = 1; off < 16; off <<= 1) {
      s0 += __shfl_xor(s0, off, 64); q0 += __shfl_xor(q0, off, 64);
      s1 += __shfl_xor(s1, off, 64); q1 += __shfl_xor(q1, off, 64);
      s2 += __shfl_xor(s2, off, 64); q2 += __shfl_xor(q2, off, 64);
      s3 += __shfl_xor(s3, off, 64); q3 += __shfl_xor(q3, off, 64);
    }
    if (llo == 0) {
      atomicAdd(&sumw[g * 256 + mloc], s0);     atomicAdd(&sqw[g * 256 + mloc], q0);
      atomicAdd(&sumw[g * 256 + mloc + 1], s1); atomicAdd(&sqw[g * 256 + mloc + 1], q1);
      atomicAdd(&sumw[g * 256 + mloc + 2], s2); atomicAdd(&sqw[g * 256 + mloc + 2], q2);
      atomicAdd(&sumw[g * 256 + mloc + 3], s3); atomicAdd(&sqw[g * 256 + mloc + 3], q3);
    }
  }
  __syncthreads();
  {
    int rr = t >> 2, cq = t & 3;
    #pragma unroll
    for (int p = 0; p < 4; p++) {
      int mr = p * 64 + rr;
      u16* yrow = Y2 + ((size_t)b * 256 + mr) * (size_t)GN_ + (size_t)g * N_ + n0;
      #pragma unroll
      for (int u = 0; u < 2; u++) {
        int s = cq * 2 + u;
        uint4 v = *(const uint4*)(smem + 32768 + mr * 128 + ((s * 16) ^ ((mr & 7) << 4)));
        *(uint4*)(yrow + s * 8) = v;
      }
    }
  }
}

// ---------------- BN apply 2: Out = relu(bn2(Y2)), f16 -> f32 ----------------
__launch_bounds__(256)
__global__ void bnapply2_kernel(const u16* __restrict__ Y2, const float2* __restrict__ ss,
                                float* __restrict__ Out)
{
  int f8 = blockIdx.x * 256 + threadIdx.x;
  size_t base = (size_t)f8 * 8;
  int m = (int)((base >> 16) & 255);
  int g = (int)((base >> 12) & 15);
  float2 sc = ss[g * 256 + m];
  uint4 yv = *(const uint4*)(Y2 + base);
  const u32* yw = (const u32*)&yv;
  float4 a, b4;
  float* av = (float*)&a;
  float* bvv = (float*)&b4;
  #pragma unroll
  for (int i = 0; i < 2; i++) {
    float2 f = __half22float2(bits2h(yw[i]));
    av[2 * i]     = fmaxf(fmaf(f.x, sc.x, sc.y), 0.f);
    av[2 * i + 1] = fmaxf(fmaf(f.y, sc.x, sc.y), 0.f);
  }
  #pragma unroll
  for (int i = 0; i < 2; i++) {
    float2 f = __half22float2(bits2h(yw[2 + i]));
    bvv[2 * i]     = fmaxf(fmaf(f.x, sc.x, sc.y), 0.f);
    bvv[2 * i + 1] = fmaxf(fmaf(f.y, sc.x, sc.y), 0.f);
  }
  *(float4*)(Out + base) = a;
  *(float4*)(Out + base + 4) = b4;
}

// ---------------- launch ----------------
extern "C" void kernel_launch(void* const* d_in, const int* in_sizes, int n_in,
                              void* d_out, int out_size, void* d_ws, size_t ws_size,
                              hipStream_t stream)
{
  (void)in_sizes; (void)n_in; (void)out_size; (void)ws_size;
  const float* xyz1    = (const float*)d_in[0];
  const float* points1 = (const float*)d_in[1];
  const float* xyz2    = (const float*)d_in[3];
  const float* points2 = (const float*)d_in[4];
  const float* W1      = (const float*)d_in[6];
  const float* b1      = (const float*)d_in[7];
  const float* gamma1  = (const float*)d_in[8];
  const float* beta1   = (const float*)d_in[9];
  const float* W2      = (const float*)d_in[10];
  const float* b2      = (const float*)d_in[11];
  const float* gamma2  = (const float*)d_in[12];
  const float* beta2   = (const float*)d_in[13];
  float* out = (float*)d_out;
  char* ws = (char*)d_ws;

  u16*    W1h   = (u16*)(ws + OFF_W1H);
  u16*    W2h   = (u16*)(ws + OFF_W2H);
  float4* xyz2p = (float4*)(ws + OFF_XYZ2P);
  float*  sum1  = (float*)(ws + OFF_SUM1);
  float*  sq1   = (float*)(ws + OFF_SQ1);
  float*  sum2  = (float*)(ws + OFF_SUM2);
  float*  sq2   = (float*)(ws + OFF_SQ2);
  u32*    scpk1 = (u32*)(ws + OFF_SCPK1);
  u32*    shpk1 = (u32*)(ws + OFF_SHPK1);
  float2* ss2   = (float2*)(ws + OFF_SS2);
  uint4*  knnp  = (uint4*)(ws + OFF_KNNP);
  u16*    p2T   = (u16*)(ws + OFF_P2T);
  u16*    Y2    = (u16*)(ws + OFF_Y2);
  u16*    Y1    = (u16*)(ws + OFF_Y1);

  prep_kernel<<<736, 256, 0, stream>>>(W1, W2, xyz2, W1h, W2h, xyz2p, sum1);
  t2_kernel<<<2048, 256, 0, stream>>>(points2, p2T);
  knn_kernel<<<512, 256, 0, stream>>>(xyz1, xyz2p, knnp);
  gemm1_kernel<<<2048, 256, 0, stream>>>(W1h, points1, p2T, knnp, b1, sum1, sq1, Y1);
  bnfin_kernel<<<16, 256, 0, stream>>>(sum1, sq1, gamma1, beta1, nullptr, scpk1, shpk1);
  gemm2_kernel<<<2048, 256, 0, stream>>>(W2h, Y1, scpk1, shpk1, b2, sum2, sq2, Y2);
  bnfin_kernel<<<16, 256, 0, stream>>>(sum2, sq2, gamma2, beta2, ss2, nullptr, nullptr);
  bnapply2_kernel<<<16384, 256, 0, stream>>>(Y2, ss2, out);
}